// Round 11
// baseline (148.721 us; speedup 1.0000x reference)
//
#include <hip/hip_runtime.h>
#include <hip/hip_bf16.h>

#define DOUT 128
#define NEG 0.01f

typedef __attribute__((ext_vector_type(8))) short bf16x8;   // 8 bf16 = 4 VGPRs
typedef __attribute__((ext_vector_type(4))) float f32x4;

__device__ __forceinline__ unsigned short f2bf(float f) {
    union { float f; unsigned int i; } c; c.f = f;
    unsigned int r = c.i + 0x7FFF + ((c.i >> 16) & 1);   // round-to-nearest-even
    return (unsigned short)(r >> 16);
}

// ---------------- prep: Wt = bf16(W^T) [dim][k] | CSR offsets ----------------
__global__ __launch_bounds__(256)
void prep_build(const float* __restrict__ W, unsigned short* __restrict__ Wt,
                const int* __restrict__ edge_dst, int* __restrict__ offsets,
                int N, int E)
{
    const int tid = threadIdx.x;
    if (blockIdx.x < 64) {
        int idx = blockIdx.x * 256 + tid;     // 0..16383
        int k = idx >> 7;                     // W row
        int d = idx & 127;                    // W col (coalesced read over d)
        Wt[(size_t)d * 128 + k] = f2bf(W[(size_t)k * 128 + d]);
        return;
    }
    int e = (blockIdx.x - 64) * 256 + tid;
    if (e < E) {
        int dd = edge_dst[e];
        int prev = (e == 0) ? -1 : edge_dst[e - 1];
        for (int n = prev + 1; n <= dd; ++n) offsets[n] = e;
        if (e == E - 1)
            for (int n = dd + 1; n <= N; ++n) offsets[n] = E;
    }
}

// ---------------- MFMA GEMM (swapped operands): C' = Wt . x^T ----------------
// A-frag = Wt rows (dims), B-frag = x rows (nodes, converted once, loop-
// invariant). C layout: col=lane&15 -> node, row=quad*4+reg -> 4 CONSECUTIVE
// dims => one 8B bf16x4 h-store per lane per d-tile (vs 32 x 2B scatter in the
// R10 orientation). Wave = 16 nodes x 128 dims; no LDS, no barriers.
__global__ __launch_bounds__(256)
void gemm_mfma(const float* __restrict__ x, const unsigned short* __restrict__ Wt,
               const float* __restrict__ b, const float* __restrict__ a_w,
               unsigned short* __restrict__ h, float* __restrict__ s_dst,
               float* __restrict__ s_src, int N)
{
    const int lane = threadIdx.x & 63;
    const int wave = threadIdx.x >> 6;
    const int m = lane & 15;              // node index within wave tile
    const int q = lane >> 4;              // quad: k-slab byte group / dim subrow
    const int r0 = blockIdx.x * 64 + wave * 16;
    const int node = r0 + m;
    const int nodel = node < N ? node : N - 1;   // clamp loads; stores predicated

    // B-frags: x[node][s*32 + q*8 .. +8] as bf16 (loop-invariant)
    bf16x8 xb[4];
    const float* xr = x + (size_t)nodel * 128;
#pragma unroll
    for (int s = 0; s < 4; ++s) {
        float4 p0 = *(const float4*)&xr[s * 32 + q * 8];
        float4 p1 = *(const float4*)&xr[s * 32 + q * 8 + 4];
        bf16x8 t;
        t[0] = (short)f2bf(p0.x); t[1] = (short)f2bf(p0.y);
        t[2] = (short)f2bf(p0.z); t[3] = (short)f2bf(p0.w);
        t[4] = (short)f2bf(p1.x); t[5] = (short)f2bf(p1.y);
        t[6] = (short)f2bf(p1.z); t[7] = (short)f2bf(p1.w);
        xb[s] = t;
    }

    float sd = 0.f, ss = 0.f;             // s partials for this lane's node

#pragma unroll 2
    for (int d = 0; d < 8; ++d) {
        const int dimA = d * 16 + m;      // A row this lane supplies
        bf16x8 af[4];
#pragma unroll
        for (int s = 0; s < 4; ++s)
            af[s] = *(const bf16x8*)&Wt[(size_t)dimA * 128 + s * 32 + q * 8];
        f32x4 acc = {0.f, 0.f, 0.f, 0.f};
#pragma unroll
        for (int s = 0; s < 4; ++s)
            acc = __builtin_amdgcn_mfma_f32_16x16x32_bf16(af[s], xb[s], acc, 0, 0, 0);

        const int dimbase = d * 16 + q * 4;       // 4 consecutive dims this lane holds
        const float4 bb  = *(const float4*)&b[dimbase];
        const float4 awd = *(const float4*)&a_w[dimbase];
        const float4 aws = *(const float4*)&a_w[DOUT + dimbase];
        float o0 = acc[0] + bb.x, o1 = acc[1] + bb.y;
        float o2 = acc[2] + bb.z, o3 = acc[3] + bb.w;
        if (node < N) {
            ushort4 hb;
            hb.x = f2bf(o0); hb.y = f2bf(o1); hb.z = f2bf(o2); hb.w = f2bf(o3);
            *(ushort4*)&h[(size_t)node * 128 + dimbase] = hb;
        }
        sd += o0 * awd.x + o1 * awd.y + o2 * awd.z + o3 * awd.w;
        ss += o0 * aws.x + o1 * aws.y + o2 * aws.z + o3 * aws.w;
    }

    // reduce s across the 4 quad-groups (lanes m, m+16, m+32, m+48 share node)
    sd += __shfl_xor(sd, 16, 64); sd += __shfl_xor(sd, 32, 64);
    ss += __shfl_xor(ss, 16, 64); ss += __shfl_xor(ss, 32, 64);
    if (q == 0 && node < N) { s_dst[node] = sd; s_src[node] = ss; }
}

// ---------------- segment softmax + aggregation: 16-lane group per node ----------------
// Single fused softmax pass (no max-subtraction: logits ~ N(0,1), exp safe).
// Pass 2 keeps 8 uint4 row-loads in flight per lane against L2/L3 latency.
#define GL 16      // lanes per group
#define KSLOT 4    // register slots -> 64 edges cached

__device__ __forceinline__ void fma8(unsigned int u0, unsigned int u1,
                                     unsigned int u2, unsigned int u3,
                                     float w, float* a) {
    union { unsigned int i; float f; } c;
    c.i = u0 << 16;         a[0] += w * c.f;
    c.i = u0 & 0xFFFF0000u; a[1] += w * c.f;
    c.i = u1 << 16;         a[2] += w * c.f;
    c.i = u1 & 0xFFFF0000u; a[3] += w * c.f;
    c.i = u2 << 16;         a[4] += w * c.f;
    c.i = u2 & 0xFFFF0000u; a[5] += w * c.f;
    c.i = u3 << 16;         a[6] += w * c.f;
    c.i = u3 & 0xFFFF0000u; a[7] += w * c.f;
}

__global__ __launch_bounds__(256)
void gat_agg(const int* __restrict__ edge_src, const int* __restrict__ offsets,
             const unsigned short* __restrict__ h, const float* __restrict__ s_src,
             const float* __restrict__ s_dst, const float* __restrict__ a_b,
             float* __restrict__ out, int N)
{
    const int lg16 = threadIdx.x & (GL - 1);            // lane within group
    const int n = blockIdx.x * 16 + (threadIdx.x >> 4); // node for this group
    const bool active = (n < N);

    int start = 0, end = 0;
    float sdn = 0.f;
    if (active) {
        start = offsets[n];
        end = offsets[n + 1];
        sdn = s_dst[n] + a_b[0];
    }
    const int deg = end - start;

    // ---- pass 1 (fused): exp weights into register slots + group sum ----
    float wr[KSLOT];
    int   sreg[KSLOT];
    float mysum = 0.f;
#pragma unroll
    for (int t = 0; t < KSLOT; ++t) {
        int i = lg16 + t * GL;
        wr[t] = 0.f; sreg[t] = 0;
        if (i < deg) {
            int s = edge_src[start + i];
            float lg = sdn + s_src[s];
            lg = lg >= 0.f ? lg : NEG * lg;
            float w = __expf(lg);
            sreg[t] = s; wr[t] = w;
            mysum += w;
        }
    }
    for (int i = lg16 + KSLOT * GL; i < deg; i += GL) {  // overflow (deg>64, ~never)
        float lg = sdn + s_src[edge_src[start + i]];
        lg = lg >= 0.f ? lg : NEG * lg;
        mysum += __expf(lg);
    }
#pragma unroll
    for (int o = 8; o; o >>= 1) mysum += __shfl_xor(mysum, o, GL);

    // ---- pass 2: gather rows; lane = 8 dims (16 lanes x 16B = 256B bf16 row) ----
    const uint4* __restrict__ h4 = (const uint4*)h;      // row stride = 16 uint4
    float a[8];
#pragma unroll
    for (int q = 0; q < 8; ++q) a[q] = 0.f;

    const int degc = deg < KSLOT * GL ? deg : KSLOT * GL;
#pragma unroll
    for (int t = 0; t < KSLOT; ++t) {
        const int base = t * GL;
        if (base >= degc) break;
        const int cnt = (degc - base) < GL ? (degc - base) : GL;
        const float wt = wr[t];
        const int   st = sreg[t];
        int j = 0;
        for (; j + 8 <= cnt; j += 8) {                   // 8 rows in flight
            float wj[8]; int sj[8]; uint4 vj[8];
#pragma unroll
            for (int q = 0; q < 8; ++q) {
                wj[q] = __shfl(wt, j + q, GL);
                sj[q] = __shfl(st, j + q, GL);
            }
#pragma unroll
            for (int q = 0; q < 8; ++q) vj[q] = h4[(size_t)sj[q] * 16 + lg16];
#pragma unroll
            for (int q = 0; q < 8; ++q) fma8(vj[q].x, vj[q].y, vj[q].z, vj[q].w, wj[q], a);
        }
        for (; j < cnt; ++j) {
            float w = __shfl(wt, j, GL); int s = __shfl(st, j, GL);
            uint4 v = h4[(size_t)s * 16 + lg16];
            fma8(v.x, v.y, v.z, v.w, w, a);
        }
    }
    for (int i = KSLOT * GL; i < deg; ++i) {             // overflow (uniform addr)
        int s = edge_src[start + i];
        float lgv = sdn + s_src[s];
        lgv = lgv >= 0.f ? lgv : NEG * lgv;
        float w = __expf(lgv);
        uint4 v = h4[(size_t)s * 16 + lg16];
        fma8(v.x, v.y, v.z, v.w, w, a);
    }

    if (active) {
        const float inv = 1.f / fmaxf(mysum, 1e-16f);
        float4 o0, o1;
        o0.x = a[0] * inv; o0.y = a[1] * inv; o0.z = a[2] * inv; o0.w = a[3] * inv;
        o1.x = a[4] * inv; o1.y = a[5] * inv; o1.z = a[6] * inv; o1.w = a[7] * inv;
        float4* op = (float4*)&out[(size_t)n * DOUT + lg16 * 8];
        op[0] = o0;
        op[1] = o1;
    }
}

extern "C" void kernel_launch(void* const* d_in, const int* in_sizes, int n_in,
                              void* d_out, int out_size, void* d_ws, size_t ws_size,
                              hipStream_t stream)
{
    const float* x        = (const float*)d_in[0];
    const int*   edge_src = (const int*)d_in[1];
    const int*   edge_dst = (const int*)d_in[2];
    const float* W        = (const float*)d_in[3];
    const float* b        = (const float*)d_in[4];
    const float* a_w      = (const float*)d_in[5];
    const float* a_b      = (const float*)d_in[6];
    const int N = in_sizes[0] / DOUT;
    const int E = in_sizes[1];
    float* out = (float*)d_out;

    char* ws = (char*)d_ws;
    unsigned short* h  = (unsigned short*)ws;  ws += (size_t)N * DOUT * sizeof(unsigned short);
    float* s_dst   = (float*)ws;  ws += (size_t)N * sizeof(float);
    float* s_src   = (float*)ws;  ws += (size_t)N * sizeof(float);
    int*   offsets = (int*)ws;    ws += (size_t)(N + 1) * sizeof(int);
    unsigned short* Wt = (unsigned short*)ws;  ws += (size_t)DOUT * DOUT * sizeof(unsigned short);

    const int buildBlocks = (E + 255) / 256;
    prep_build<<<64 + buildBlocks, 256, 0, stream>>>(W, Wt, edge_dst, offsets, N, E);
    gemm_mfma<<<(N + 63) / 64, 256, 0, stream>>>(x, Wt, b, a_w, h, s_dst, s_src, N);
    gat_agg<<<(N + 15) / 16, 256, 0, stream>>>(edge_src, offsets, h, s_src, s_dst, a_b, out, N);
}

// Round 12
// 136.789 us; speedup vs baseline: 1.0872x; 1.0872x over previous
//
#include <hip/hip_runtime.h>
#include <hip/hip_bf16.h>

#define DOUT 128
#define NEG 0.01f

typedef __attribute__((ext_vector_type(8))) short bf16x8;   // 8 bf16 = 4 VGPRs
typedef __attribute__((ext_vector_type(4))) float f32x4;

__device__ __forceinline__ unsigned short f2bf(float f) {
    union { float f; unsigned int i; } c; c.f = f;
    unsigned int r = c.i + 0x7FFF + ((c.i >> 16) & 1);   // round-to-nearest-even
    return (unsigned short)(r >> 16);
}

// ---------------- prep: Wt = bf16(W^T) [dim][k] | CSR offsets ----------------
__global__ __launch_bounds__(256)
void prep_build(const float* __restrict__ W, unsigned short* __restrict__ Wt,
                const int* __restrict__ edge_dst, int* __restrict__ offsets,
                int N, int E)
{
    const int tid = threadIdx.x;
    if (blockIdx.x < 64) {
        int idx = blockIdx.x * 256 + tid;     // 0..16383
        int k = idx >> 7;                     // W row
        int d = idx & 127;                    // W col (coalesced read over d)
        Wt[(size_t)d * 128 + k] = f2bf(W[(size_t)k * 128 + d]);
        return;
    }
    int e = (blockIdx.x - 64) * 256 + tid;
    if (e < E) {
        int dd = edge_dst[e];
        int prev = (e == 0) ? -1 : edge_dst[e - 1];
        for (int n = prev + 1; n <= dd; ++n) offsets[n] = e;
        if (e == E - 1)
            for (int n = dd + 1; n <= N; ++n) offsets[n] = E;
    }
}

// ---------------- MFMA GEMM: C' = Wt . x^T, Wt staged in LDS ----------------
// R11 re-read Wt from global per d-iter (100 MB through an L1 thrashed by the
// x stream -> ~200cyc exposed per iter). Stage Wt in LDS once (32KB, one
// barrier); row stride padded to 136 halfwords so quad lanes hit 4-dword bank
// groups pairwise (2-way conflict = free). Each wave reads Wt exactly once.
// C layout: col=lane&15 -> node, row=quad*4+reg -> 4 consecutive dims
// => one 8B bf16x4 h-store per lane per d-tile.
#define WROW 136   // padded LDS row stride in halfwords

__global__ __launch_bounds__(256)
void gemm_mfma(const float* __restrict__ x, const unsigned short* __restrict__ Wt,
               const float* __restrict__ b, const float* __restrict__ a_w,
               unsigned short* __restrict__ h, float* __restrict__ s_dst,
               float* __restrict__ s_src, int N)
{
    __shared__ unsigned short Wl[128 * WROW];   // 34.8 KB
    const int tid = threadIdx.x;
    const int lane = tid & 63;
    const int wave = tid >> 6;

    // stage Wt -> LDS: 2048 uint4, 8 per thread, coalesced global / clean LDS banks
#pragma unroll
    for (int i = 0; i < 8; ++i) {
        int gidx = i * 256 + tid;             // uint4 index, 16 per row
        int r = gidx >> 4;
        int c = (gidx & 15) << 3;             // halfword col
        uint4 v = *(const uint4*)&Wt[(size_t)r * 128 + c];
        *(uint4*)&Wl[r * WROW + c] = v;
    }

    const int m = lane & 15;              // node index within wave tile
    const int q = lane >> 4;              // quad
    const int r0 = blockIdx.x * 64 + wave * 16;
    const int node = r0 + m;
    const int nodel = node < N ? node : N - 1;   // clamp loads; stores predicated

    // B-frags: x[node][s*32 + q*8 .. +8] as bf16 (loop-invariant)
    bf16x8 xb[4];
    const float* xr = x + (size_t)nodel * 128;
#pragma unroll
    for (int s = 0; s < 4; ++s) {
        float4 p0 = *(const float4*)&xr[s * 32 + q * 8];
        float4 p1 = *(const float4*)&xr[s * 32 + q * 8 + 4];
        bf16x8 t;
        t[0] = (short)f2bf(p0.x); t[1] = (short)f2bf(p0.y);
        t[2] = (short)f2bf(p0.z); t[3] = (short)f2bf(p0.w);
        t[4] = (short)f2bf(p1.x); t[5] = (short)f2bf(p1.y);
        t[6] = (short)f2bf(p1.z); t[7] = (short)f2bf(p1.w);
        xb[s] = t;
    }

    __syncthreads();                      // Wl ready

    float sd = 0.f, ss = 0.f;             // s partials for this lane's node

#pragma unroll 2
    for (int d = 0; d < 8; ++d) {
        const int dimA = d * 16 + m;      // A row this lane supplies
        bf16x8 af[4];
#pragma unroll
        for (int s = 0; s < 4; ++s)
            af[s] = *(const bf16x8*)&Wl[dimA * WROW + s * 32 + q * 8];
        f32x4 acc = {0.f, 0.f, 0.f, 0.f};
#pragma unroll
        for (int s = 0; s < 4; ++s)
            acc = __builtin_amdgcn_mfma_f32_16x16x32_bf16(af[s], xb[s], acc, 0, 0, 0);

        const int dimbase = d * 16 + q * 4;       // 4 consecutive dims this lane holds
        const float4 bb  = *(const float4*)&b[dimbase];
        const float4 awd = *(const float4*)&a_w[dimbase];
        const float4 aws = *(const float4*)&a_w[DOUT + dimbase];
        float o0 = acc[0] + bb.x, o1 = acc[1] + bb.y;
        float o2 = acc[2] + bb.z, o3 = acc[3] + bb.w;
        if (node < N) {
            ushort4 hb;
            hb.x = f2bf(o0); hb.y = f2bf(o1); hb.z = f2bf(o2); hb.w = f2bf(o3);
            *(ushort4*)&h[(size_t)node * 128 + dimbase] = hb;
        }
        sd += o0 * awd.x + o1 * awd.y + o2 * awd.z + o3 * awd.w;
        ss += o0 * aws.x + o1 * aws.y + o2 * aws.z + o3 * aws.w;
    }

    // reduce s across the 4 quad-groups (lanes m, m+16, m+32, m+48 share node)
    sd += __shfl_xor(sd, 16, 64); sd += __shfl_xor(sd, 32, 64);
    ss += __shfl_xor(ss, 16, 64); ss += __shfl_xor(ss, 32, 64);
    if (q == 0 && node < N) { s_dst[node] = sd; s_src[node] = ss; }
}

// ---------------- segment softmax + aggregation: 16-lane group per node ----------------
// Single fused softmax pass (no max-subtraction: logits ~ N(0,1), exp safe).
// Pass 2 keeps 8 uint4 row-loads in flight per lane against L2/L3 latency.
#define GL 16      // lanes per group
#define KSLOT 4    // register slots -> 64 edges cached

__device__ __forceinline__ void fma8(unsigned int u0, unsigned int u1,
                                     unsigned int u2, unsigned int u3,
                                     float w, float* a) {
    union { unsigned int i; float f; } c;
    c.i = u0 << 16;         a[0] += w * c.f;
    c.i = u0 & 0xFFFF0000u; a[1] += w * c.f;
    c.i = u1 << 16;         a[2] += w * c.f;
    c.i = u1 & 0xFFFF0000u; a[3] += w * c.f;
    c.i = u2 << 16;         a[4] += w * c.f;
    c.i = u2 & 0xFFFF0000u; a[5] += w * c.f;
    c.i = u3 << 16;         a[6] += w * c.f;
    c.i = u3 & 0xFFFF0000u; a[7] += w * c.f;
}

__global__ __launch_bounds__(256)
void gat_agg(const int* __restrict__ edge_src, const int* __restrict__ offsets,
             const unsigned short* __restrict__ h, const float* __restrict__ s_src,
             const float* __restrict__ s_dst, const float* __restrict__ a_b,
             float* __restrict__ out, int N)
{
    const int lg16 = threadIdx.x & (GL - 1);            // lane within group
    const int n = blockIdx.x * 16 + (threadIdx.x >> 4); // node for this group
    const bool active = (n < N);

    int start = 0, end = 0;
    float sdn = 0.f;
    if (active) {
        start = offsets[n];
        end = offsets[n + 1];
        sdn = s_dst[n] + a_b[0];
    }
    const int deg = end - start;

    // ---- pass 1 (fused): exp weights into register slots + group sum ----
    float wr[KSLOT];
    int   sreg[KSLOT];
    float mysum = 0.f;
#pragma unroll
    for (int t = 0; t < KSLOT; ++t) {
        int i = lg16 + t * GL;
        wr[t] = 0.f; sreg[t] = 0;
        if (i < deg) {
            int s = edge_src[start + i];
            float lg = sdn + s_src[s];
            lg = lg >= 0.f ? lg : NEG * lg;
            float w = __expf(lg);
            sreg[t] = s; wr[t] = w;
            mysum += w;
        }
    }
    for (int i = lg16 + KSLOT * GL; i < deg; i += GL) {  // overflow (deg>64, ~never)
        float lg = sdn + s_src[edge_src[start + i]];
        lg = lg >= 0.f ? lg : NEG * lg;
        mysum += __expf(lg);
    }
#pragma unroll
    for (int o = 8; o; o >>= 1) mysum += __shfl_xor(mysum, o, GL);

    // ---- pass 2: gather rows; lane = 8 dims (16 lanes x 16B = 256B bf16 row) ----
    const uint4* __restrict__ h4 = (const uint4*)h;      // row stride = 16 uint4
    float a[8];
#pragma unroll
    for (int q = 0; q < 8; ++q) a[q] = 0.f;

    const int degc = deg < KSLOT * GL ? deg : KSLOT * GL;
#pragma unroll
    for (int t = 0; t < KSLOT; ++t) {
        const int base = t * GL;
        if (base >= degc) break;
        const int cnt = (degc - base) < GL ? (degc - base) : GL;
        const float wt = wr[t];
        const int   st = sreg[t];
        int j = 0;
        for (; j + 8 <= cnt; j += 8) {                   // 8 rows in flight
            float wj[8]; int sj[8]; uint4 vj[8];
#pragma unroll
            for (int q = 0; q < 8; ++q) {
                wj[q] = __shfl(wt, j + q, GL);
                sj[q] = __shfl(st, j + q, GL);
            }
#pragma unroll
            for (int q = 0; q < 8; ++q) vj[q] = h4[(size_t)sj[q] * 16 + lg16];
#pragma unroll
            for (int q = 0; q < 8; ++q) fma8(vj[q].x, vj[q].y, vj[q].z, vj[q].w, wj[q], a);
        }
        for (; j < cnt; ++j) {
            float w = __shfl(wt, j, GL); int s = __shfl(st, j, GL);
            uint4 v = h4[(size_t)s * 16 + lg16];
            fma8(v.x, v.y, v.z, v.w, w, a);
        }
    }
    for (int i = KSLOT * GL; i < deg; ++i) {             // overflow (uniform addr)
        int s = edge_src[start + i];
        float lgv = sdn + s_src[s];
        lgv = lgv >= 0.f ? lgv : NEG * lgv;
        float w = __expf(lgv);
        uint4 v = h4[(size_t)s * 16 + lg16];
        fma8(v.x, v.y, v.z, v.w, w, a);
    }

    if (active) {
        const float inv = 1.f / fmaxf(mysum, 1e-16f);
        float4 o0, o1;
        o0.x = a[0] * inv; o0.y = a[1] * inv; o0.z = a[2] * inv; o0.w = a[3] * inv;
        o1.x = a[4] * inv; o1.y = a[5] * inv; o1.z = a[6] * inv; o1.w = a[7] * inv;
        float4* op = (float4*)&out[(size_t)n * DOUT + lg16 * 8];
        op[0] = o0;
        op[1] = o1;
    }
}

extern "C" void kernel_launch(void* const* d_in, const int* in_sizes, int n_in,
                              void* d_out, int out_size, void* d_ws, size_t ws_size,
                              hipStream_t stream)
{
    const float* x        = (const float*)d_in[0];
    const int*   edge_src = (const int*)d_in[1];
    const int*   edge_dst = (const int*)d_in[2];
    const float* W        = (const float*)d_in[3];
    const float* b        = (const float*)d_in[4];
    const float* a_w      = (const float*)d_in[5];
    const float* a_b      = (const float*)d_in[6];
    const int N = in_sizes[0] / DOUT;
    const int E = in_sizes[1];
    float* out = (float*)d_out;

    char* ws = (char*)d_ws;
    unsigned short* h  = (unsigned short*)ws;  ws += (size_t)N * DOUT * sizeof(unsigned short);
    float* s_dst   = (float*)ws;  ws += (size_t)N * sizeof(float);
    float* s_src   = (float*)ws;  ws += (size_t)N * sizeof(float);
    int*   offsets = (int*)ws;    ws += (size_t)(N + 1) * sizeof(int);
    unsigned short* Wt = (unsigned short*)ws;  ws += (size_t)DOUT * DOUT * sizeof(unsigned short);

    const int buildBlocks = (E + 255) / 256;
    prep_build<<<64 + buildBlocks, 256, 0, stream>>>(W, Wt, edge_dst, offsets, N, E);
    gemm_mfma<<<(N + 63) / 64, 256, 0, stream>>>(x, Wt, b, a_w, h, s_dst, s_src, N);
    gat_agg<<<(N + 15) / 16, 256, 0, stream>>>(edge_src, offsets, h, s_src, s_dst, a_b, out, N);
}